// Round 4
// baseline (33.897 us; speedup 1.0000x reference)
//
#include <hip/hip_runtime.h>
#include <math.h>

// B=4, 3 anchors, 85 ch. Layers: g=10/20/40 -> P=300/1200/4800 positions per image.
// Grid: 256-thread blocks, each owns a 256-position chunk of one (layer,img):
//   l0: 2 blocks/img * 4 = 8   (blk 0..7)
//   l1: 5 blocks/img * 4 = 20  (blk 8..27)
//   l2: 19 blocks/img * 4 = 76 (blk 28..103)
#define NBLK 104
#define SCAP 512   // LDS box-list capacity (expected max ~96+; 40 sigma margin)

__device__ __constant__ float c_anc[3][3][2] = {
  {{116.f, 90.f}, {156.f, 198.f}, {373.f, 326.f}},
  {{ 30.f, 61.f}, { 62.f,  45.f}, { 59.f, 119.f}},
  {{ 10.f, 13.f}, { 16.f,  30.f}, { 33.f,  23.f}}};

__device__ __forceinline__ float bce_f(float label, float logit) {
    return fmaxf(logit, 0.0f) - logit * label + log1pf(expf(-fabsf(logit)));
}

template<int P, int G>
__device__ __forceinline__ float layer_block(
    const float* __restrict__ t, const float* __restrict__ y,
    int img, int chunk, const float (*anc)[2],
    float4* sbox, int* scount)
{
    const float* tslab = t + (size_t)img * P * 85;
    const float* yslab = y + (size_t)img * P * 85;

    // --- phase 1: build this image's target-box list in LDS (order irrelevant) ---
    if (threadIdx.x == 0) *scount = 0;
    __syncthreads();
    #pragma unroll 4
    for (int k = threadIdx.x; k < P; k += 256) {
        float obj = tslab[(size_t)k * 85 + 4];
        if (obj != 0.0f) {
            int off = atomicAdd(scount, 1);
            if (off < SCAP) {
                const float* tp = tslab + (size_t)k * 85;
                sbox[off] = make_float4(tp[0], tp[1], tp[2], tp[3]);
            }
        }
    }
    __syncthreads();
    int cnt = *scount; if (cnt > SCAP) cnt = SCAP;
    int cntPad = (cnt + 7) & ~7;            // zero-pad: iou(0-box)=0, harmless
    for (int k = cnt + threadIdx.x; k < cntPad; k += 256)
        sbox[k] = make_float4(0.f, 0.f, 0.f, 0.f);
    __syncthreads();

    // --- phase 2: conf term for this thread's position (uniform flow) ---
    int pos = chunk * 256 + threadIdx.x;
    bool valid = pos < P;
    float acc = 0.0f, obj = 0.0f;
    if (valid) {
        const float* yp = yslab + (size_t)pos * 85;
        obj = tslab[(size_t)pos * 85 + 4];
        float q0 = yp[0], q1 = yp[1], q2 = yp[2], q3 = yp[3], q4 = yp[4];
        int a = pos % 3, cell = pos / 3;
        int j = cell % G, i = cell / G;
        float aw = anc[a][0], ah = anc[a][1];
        float gi = (float)G;

        float px = (1.0f / (1.0f + expf(-q0)) + (float)j) / gi;
        float py = (1.0f / (1.0f + expf(-q1)) + (float)i) / gi;
        float pw = expf(q2) * aw * (1.0f / 320.0f);
        float ph = expf(q3) * ah * (1.0f / 320.0f);
        float phx = pw * 0.5f, phy = ph * 0.5f;
        float pminx = px - phx, pmaxx = px + phx;
        float pminy = py - phy, pmaxy = py + phy;
        float parea = pw * ph;

        float best = -INFINITY;
        for (int k0 = 0; k0 < cntPad; k0 += 8) {
            #pragma unroll
            for (int u = 0; u < 8; ++u) {
                float4 tb = sbox[k0 + u];
                float thx = tb.z * 0.5f, thy = tb.w * 0.5f;
                float wx = fminf(pmaxx, tb.x + thx) - fmaxf(pminx, tb.x - thx);
                float wy = fminf(pmaxy, tb.y + thy) - fmaxf(pminy, tb.y - thy);
                wx = fmaxf(wx, 0.0f);
                wy = fmaxf(wy, 0.0f);
                float inter = wx * wy;
                float iou = inter / (parea + tb.z * tb.w - inter);
                best = fmaxf(best, iou);
            }
        }
        float ignore = (best < 0.5f) ? 1.0f : 0.0f;
        float bce_c = fmaxf(q4, 0.0f) - q4 * obj + log1pf(expf(-fabsf(q4)));
        acc = (obj + (1.0f - obj) * ignore) * bce_c;   // gate==1 for positives
    }

    // --- phase 3: positives in this wave's 64 positions, whole-wave per-channel ---
    unsigned long long m = __ballot(valid && obj != 0.0f);
    int lane = threadIdx.x & 63;
    int waveBase = chunk * 256 + (threadIdx.x & ~63);
    while (m) {
        int b = __ffsll(m) - 1; m &= m - 1;
        int ppos = waveBase + b;
        const float* tp = tslab + (size_t)ppos * 85;
        const float* yp = yslab + (size_t)ppos * 85;
        float tv1 = tp[lane], yv1 = yp[lane];          // ch 0..63 (coalesced)
        bool has2 = lane < 21;
        float tv2 = 0.f, yv2 = 0.f;
        if (has2) { tv2 = tp[lane + 64]; yv2 = yp[lane + 64]; }  // ch 64..84

        float tw = __shfl(tv1, 2, 64);
        float th = __shfl(tv1, 3, 64);
        float bs = 2.0f - tw * th;
        int a = ppos % 3, cell = ppos / 3;
        int jj = cell % G, ii = cell / G;
        float aw = anc[a][0], ah = anc[a][1];

        float term;
        if (lane == 0)      term = bs * bce_f(tv1 * (float)G - (float)jj, yv1);
        else if (lane == 1) term = bs * bce_f(tv1 * (float)G - (float)ii, yv1);
        else if (lane == 2) { float d = logf(tv1 * 320.0f / aw) - yv1; term = bs * 0.5f * d * d; }
        else if (lane == 3) { float d = logf(tv1 * 320.0f / ah) - yv1; term = bs * 0.5f * d * d; }
        else if (lane == 4) term = 0.0f;               // conf for positives already in phase 2
        else                term = bce_f(tv1, yv1);    // cls 5..63
        if (has2) term += bce_f(tv2, yv2);             // cls 64..84
        acc += term;
    }
    return acc;
}

__global__ __launch_bounds__(256) void k_all(
    const float* __restrict__ t0, const float* __restrict__ y0,
    const float* __restrict__ t1, const float* __restrict__ y1,
    const float* __restrict__ t2, const float* __restrict__ y2,
    float* __restrict__ partials)
{
    __shared__ float4 sbox[SCAP];
    __shared__ int scount;
    int blk = blockIdx.x;

    float acc;
    if (blk < 8)       acc = layer_block< 300, 10>(t0, y0, blk >> 1, blk & 1,  c_anc[0], sbox, &scount);
    else if (blk < 28) { int r = blk - 8;  acc = layer_block<1200, 20>(t1, y1, r / 5,  r % 5,  c_anc[1], sbox, &scount); }
    else               { int r = blk - 28; acc = layer_block<4800, 40>(t2, y2, r / 19, r % 19, c_anc[2], sbox, &scount); }

    // block reduce -> one partial per block (no global atomics)
    float v = acc;
    #pragma unroll
    for (int o = 32; o > 0; o >>= 1) v += __shfl_down(v, o, 64);
    __shared__ float red[4];
    int lane = threadIdx.x & 63, w = threadIdx.x >> 6;
    if (lane == 0) red[w] = v;
    __syncthreads();
    if (threadIdx.x == 0)
        partials[blk] = ((red[0] + red[1]) + (red[2] + red[3])) * 0.25f;  // mean over B=4
}

__global__ __launch_bounds__(128) void k_fin(
    const float* __restrict__ partials, float* __restrict__ out)
{
    int tid = threadIdx.x;
    float s = (tid < NBLK) ? partials[tid] : 0.0f;
    #pragma unroll
    for (int o = 32; o > 0; o >>= 1) s += __shfl_down(s, o, 64);
    __shared__ float r2[2];
    if ((tid & 63) == 0) r2[tid >> 6] = s;
    __syncthreads();
    if (tid == 0) out[0] = r2[0] + r2[1];
}

extern "C" void kernel_launch(void* const* d_in, const int* in_sizes, int n_in,
                              void* d_out, int out_size, void* d_ws, size_t ws_size,
                              hipStream_t stream) {
    // setup_inputs dict order: t0, y0, t1, y1, t2, y2
    const float* t0 = (const float*)d_in[0];
    const float* y0 = (const float*)d_in[1];
    const float* t1 = (const float*)d_in[2];
    const float* y1 = (const float*)d_in[3];
    const float* t2 = (const float*)d_in[4];
    const float* y2 = (const float*)d_in[5];

    float* partials = (float*)d_ws;   // NBLK floats, every slot written each call
    float* out      = (float*)d_out;

    k_all<<<NBLK, 256, 0, stream>>>(t0, y0, t1, y1, t2, y2, partials);
    k_fin<<<1, 128, 0, stream>>>(partials, out);
}